// Round 10
// baseline (149.296 us; speedup 1.0000x reference)
//
#include <hip/hip_runtime.h>
#include <math.h>

#define NUM_EMB 512
#define EDIM 64
#define BATCH 32
#define HW 4096
#define NROWS (BATCH * HW)        // 131072
#define NQ (NROWS * EDIM)         // 8388608

#define RPB 128                   // rows per block
#define KPP 128                   // k per pass
#define NPASS 4

// LDS layout in floats (total 17024 floats = 68096 B -> 2 blocks/CU)
#define XOFF 0                    // x_t[c][r] : c*128 + r   (64 x 128)
#define EOFF 8192                 // e_t[c][k] : c*128 + k   (64 x 128, per pass)
#define T2OFF 16384               // t2s[512]
#define T1OFF 16896               // t1s[128]
#define CBOFF 8192                // combine best  [kt][128] (overlays e_t)
#define CKOFF (8192 + 2048)       // combine bestk [kt][128] (int, overlays e_t)
#define SFLOATS 17024

// numpy pairwise_sum for n=64 contiguous fp32 (tiny prep kernel only).
__device__ __forceinline__ float pairwise8_64(const float* v) {
    float r0 = v[0], r1 = v[1], r2 = v[2], r3 = v[3];
    float r4 = v[4], r5 = v[5], r6 = v[6], r7 = v[7];
#pragma unroll
    for (int i = 8; i < 64; i += 8) {
        r0 = __fadd_rn(r0, v[i + 0]);
        r1 = __fadd_rn(r1, v[i + 1]);
        r2 = __fadd_rn(r2, v[i + 2]);
        r3 = __fadd_rn(r3, v[i + 3]);
        r4 = __fadd_rn(r4, v[i + 4]);
        r5 = __fadd_rn(r5, v[i + 5]);
        r6 = __fadd_rn(r6, v[i + 6]);
        r7 = __fadd_rn(r7, v[i + 7]);
    }
    return __fadd_rn(__fadd_rn(__fadd_rn(r0, r1), __fadd_rn(r2, r3)),
                     __fadd_rn(__fadd_rn(r4, r5), __fadd_rn(r6, r7)));
}

// ws_f layout: [0] = loss sum accumulator, [8..8+511] = t2[k] = ||emb_k||^2
__global__ void vq_prep(const float* __restrict__ emb, float* __restrict__ ws_f) {
    int k = blockIdx.x * blockDim.x + threadIdx.x;
    if (k == 0) ws_f[0] = 0.0f;
    if (k < NUM_EMB) {
        const float* e = emb + k * EDIM;
        float sq[EDIM];
#pragma unroll
        for (int c = 0; c < EDIM; ++c) sq[c] = __fmul_rn(e[c], e[c]);
        ws_f[8 + k] = pairwise8_64(sq);
    }
}

// Round-10: tile sized to what the allocator will actually keep (acc[4][8],
// ~75 live regs) + occupancy doubled (68KB LDS -> 2 blocks/CU -> 4 waves/EU).
// 512 threads = 32 row-threads x 16 k-threads; 4 passes of 128 k.
// Per (row,k): ONE sequential ascending-c FMA chain -> bit-exact vs numpy.
__global__ __launch_bounds__(512, 4) void vq_main(const float* __restrict__ z,
                                                  const float* __restrict__ emb,
                                                  float* __restrict__ out,
                                                  float* __restrict__ ws_f) {
    __shared__ float S[SFLOATS];
    const int tid = threadIdx.x;
    const int rt  = tid & 31;        // row-thread: rows rt*4 .. rt*4+3
    const int kt  = tid >> 5;        // k-thread: 16 of them, 8 k each per pass
    const int row0 = rt * 4;
    const int bb  = blockIdx.x;
    const int b   = bb >> 5;         // 32 blocks per batch image
    const int hwb = (bb & 31) << 7;  // block's hw base (128 rows)

    const float* zb = z + (size_t)b * (EDIM * HW) + hwb;

    // ---- stage x_t[c][r] (transposed) + t2s ----
    {
        const int r = tid & 127, ch = tid >> 7;   // ch 0..3 -> 16 c's each
#pragma unroll
        for (int j = 0; j < 16; ++j) {
            const int c = ch * 16 + j;
            S[XOFF + c * RPB + r] = zb[(size_t)c * HW + r];  // coalesced lanes->r
        }
    }
    S[T2OFF + tid] = ws_f[8 + tid];
    __syncthreads();

    // ---- t1 per row: numpy pairwise-8, ascending c, from x_t ----
    if (tid < RPB) {
        const float* xr = &S[XOFF + tid];   // stride RPB per c
        float q0 = __fmul_rn(xr[0 * RPB], xr[0 * RPB]);
        float q1 = __fmul_rn(xr[1 * RPB], xr[1 * RPB]);
        float q2 = __fmul_rn(xr[2 * RPB], xr[2 * RPB]);
        float q3 = __fmul_rn(xr[3 * RPB], xr[3 * RPB]);
        float q4 = __fmul_rn(xr[4 * RPB], xr[4 * RPB]);
        float q5 = __fmul_rn(xr[5 * RPB], xr[5 * RPB]);
        float q6 = __fmul_rn(xr[6 * RPB], xr[6 * RPB]);
        float q7 = __fmul_rn(xr[7 * RPB], xr[7 * RPB]);
#pragma unroll
        for (int m = 1; m < 8; ++m) {
            float v0 = xr[(8 * m + 0) * RPB], v1 = xr[(8 * m + 1) * RPB];
            float v2 = xr[(8 * m + 2) * RPB], v3 = xr[(8 * m + 3) * RPB];
            float v4 = xr[(8 * m + 4) * RPB], v5 = xr[(8 * m + 5) * RPB];
            float v6 = xr[(8 * m + 6) * RPB], v7 = xr[(8 * m + 7) * RPB];
            q0 = __fadd_rn(q0, __fmul_rn(v0, v0));
            q1 = __fadd_rn(q1, __fmul_rn(v1, v1));
            q2 = __fadd_rn(q2, __fmul_rn(v2, v2));
            q3 = __fadd_rn(q3, __fmul_rn(v3, v3));
            q4 = __fadd_rn(q4, __fmul_rn(v4, v4));
            q5 = __fadd_rn(q5, __fmul_rn(v5, v5));
            q6 = __fadd_rn(q6, __fmul_rn(v6, v6));
            q7 = __fadd_rn(q7, __fmul_rn(v7, v7));
        }
        S[T1OFF + tid] = __fadd_rn(__fadd_rn(__fadd_rn(q0, q1), __fadd_rn(q2, q3)),
                                   __fadd_rn(__fadd_rn(q4, q5), __fadd_rn(q6, q7)));
    }
    __syncthreads();

    float t1r[4];
#pragma unroll
    for (int i = 0; i < 4; ++i) t1r[i] = S[T1OFF + row0 + i];

    float best[4];
    int   bki[4];
#pragma unroll
    for (int i = 0; i < 4; ++i) { best[i] = INFINITY; bki[i] = 0; }

    const int kb = kt * 8;           // this thread's k offset within a pass

    // ---- four passes over the codebook (128 k each) ----
    for (int p = 0; p < NPASS; ++p) {
        // stage e_t[c][k] (transposed); lanes write consecutive k -> no conflict
        {
            const int k = tid & 127, ch = tid >> 7;
            const float4* er = (const float4*)(emb + (size_t)(p * KPP + k) * EDIM);
#pragma unroll
            for (int j = 0; j < 4; ++j) {
                const float4 v = er[ch * 4 + j];
                const int c = ch * 16 + j * 4;
                S[EOFF + (c + 0) * KPP + k] = v.x;
                S[EOFF + (c + 1) * KPP + k] = v.y;
                S[EOFF + (c + 2) * KPP + k] = v.z;
                S[EOFF + (c + 3) * KPP + k] = v.w;
            }
        }
        __syncthreads();

        float acc[4][8];
#pragma unroll
        for (int i = 0; i < 4; ++i)
#pragma unroll
            for (int j = 0; j < 8; ++j) acc[i][j] = 0.0f;

#pragma unroll 4
        for (int c = 0; c < 64; ++c) {
            // lanes 0..31 -> consecutive float4s (byte 16*lane): conflict-free;
            // lanes 32..63 duplicate them: broadcast.
            const float4 xa = *(const float4*)&S[XOFF + c * RPB + row0];
            // half-wave-uniform addresses -> LDS broadcast
            const float4 e0 = *(const float4*)&S[EOFF + c * KPP + kb];
            const float4 e1 = *(const float4*)&S[EOFF + c * KPP + kb + 4];
#define ROW(i, xv) \
            acc[i][0] = __fmaf_rn(xv, e0.x, acc[i][0]); \
            acc[i][1] = __fmaf_rn(xv, e0.y, acc[i][1]); \
            acc[i][2] = __fmaf_rn(xv, e0.z, acc[i][2]); \
            acc[i][3] = __fmaf_rn(xv, e0.w, acc[i][3]); \
            acc[i][4] = __fmaf_rn(xv, e1.x, acc[i][4]); \
            acc[i][5] = __fmaf_rn(xv, e1.y, acc[i][5]); \
            acc[i][6] = __fmaf_rn(xv, e1.z, acc[i][6]); \
            acc[i][7] = __fmaf_rn(xv, e1.w, acc[i][7]);
            ROW(0, xa.x) ROW(1, xa.y) ROW(2, xa.z) ROW(3, xa.w)
#undef ROW
        }

        // finish: d = fl(fl(t1 + t2) - fl(2*p)); in-thread k ascending,
        // pass order ascending -> strict < keeps lowest index
#pragma unroll
        for (int j = 0; j < 8; ++j) {
            const int kg = p * KPP + kb + j;
            const float t2k = S[T2OFF + kg];
#pragma unroll
            for (int i = 0; i < 4; ++i) {
                float d = __fsub_rn(__fadd_rn(t1r[i], t2k),
                                    __fmul_rn(2.0f, acc[i][j]));
                if (d < best[i]) { best[i] = d; bki[i] = kg; }
            }
        }
        __syncthreads();   // e_t consumed; safe to restage / overlay
    }

    // ---- combine across the 16 k-threads (overlay on e_t region) ----
#pragma unroll
    for (int i = 0; i < 4; ++i) {
        S[CBOFF + kt * RPB + row0 + i] = best[i];
        ((int*)S)[CKOFF + kt * RPB + row0 + i] = bki[i];
    }
    __syncthreads();

    if (tid < RPB) {
        const int row = tid;
        float B = INFINITY;
        int   K = 0;
        // lexicographic (d, k) min == numpy argmin lowest-index tie-break,
        // required because the kt partition interleaves k ranges.
#pragma unroll
        for (int q = 0; q < 16; ++q) {
            const float bq = S[CBOFF + q * RPB + row];
            const int   kq = ((int*)S)[CKOFF + q * RPB + row];
            if (bq < B || (bq == B && kq < K)) { B = bq; K = kq; }
        }

        // epilogue: qst = fl(x + fl(q - x)), loss partial, idx
        const float* eb = emb + (size_t)K * EDIM;
        const float* xc = &S[XOFF + row];
        float s = 0.0f;
#pragma unroll
        for (int c = 0; c < 64; ++c) {
            const float x = xc[c * RPB];
            const float f = __fsub_rn(eb[c], x);
            out[((size_t)b * EDIM + c) * HW + hwb + row] = __fadd_rn(x, f);
            s = __fmaf_rn(f, f, s);
        }
        out[(size_t)NQ + 2 + bb * RPB + row] = (float)K;

        // two full waves (tid 0..127) -> wave shuffle + one atomic per wave
#pragma unroll
        for (int off = 32; off > 0; off >>= 1) s += __shfl_down(s, off);
        if ((tid & 63) == 0) atomicAdd(ws_f, s);
    }
}

__global__ void vq_final(const float* __restrict__ ws_f, float* __restrict__ out) {
    float m = ws_f[0] * (1.0f / (float)NQ);   // 2^-23, exact scaling
    out[NQ + 0] = m;
    out[NQ + 1] = m;
}

extern "C" void kernel_launch(void* const* d_in, const int* in_sizes, int n_in,
                              void* d_out, int out_size, void* d_ws, size_t ws_size,
                              hipStream_t stream) {
    const float* z = (const float*)d_in[0];     // [32, 64, 64, 64] fp32
    const float* emb = (const float*)d_in[1];   // [512, 64] fp32
    float* out = (float*)d_out;
    float* ws_f = (float*)d_ws;

    hipLaunchKernelGGL(vq_prep, dim3(1), dim3(512), 0, stream, emb, ws_f);
    hipLaunchKernelGGL(vq_main, dim3(NROWS / RPB), dim3(512), 0, stream, z, emb, out, ws_f);
    hipLaunchKernelGGL(vq_final, dim3(1), dim3(1), 0, stream, ws_f, out);
}